// Round 1
// baseline (105.712 us; speedup 1.0000x reference)
//
#include <hip/hip_runtime.h>
#include <math.h>

#define QHn 128
#define QWn 128
#define Qn  16384
#define Hn  64
#define Wn  64
#define Cn  64
#define Bn  4
#define HIDn 256
#define OUTn 1728   // C*9*3
#define EPSf 1e-6f

// Reference-faithful coordinate math (fp32, same op order/rounding as jnp).
__device__ __forceinline__ void coord_math(const float* __restrict__ coord,
                                           const float* __restrict__ cell,
                                           int b, int q,
                                           int& iy, int& ix,
                                           float& rely, float& relx, float& rrev) {
    const size_t base = ((size_t)b * Qn + q) * 2;
    const float cy = coord[base + 0];
    const float cx = coord[base + 1];
    const float ey = cell[base + 0];
    const float ex = cell[base + 1];
    const float c_y = cy - ey * 0.5f;
    const float c_x = cx - ex * 0.5f;
    const float cqy = fminf(fmaxf(c_y + EPSf, -1.0f + EPSf), 1.0f - EPSf);
    const float cqx = fminf(fmaxf(c_x + EPSf, -1.0f + EPSf), 1.0f - EPSf);
    // round-half-even == jnp.round
    float fy = rintf(((cqy + 1.0f) * (float)Hn - 1.0f) * 0.5f);
    float fx = rintf(((cqx + 1.0f) * (float)Wn - 1.0f) * 0.5f);
    fy = fminf(fmaxf(fy, 0.0f), (float)(Hn - 1));
    fx = fminf(fmaxf(fx, 0.0f), (float)(Wn - 1));
    iy = (int)fy;
    ix = (int)fx;
    const float qcy = -1.0f + 2.0f * fy / (float)Hn;
    const float qcx = -1.0f + 2.0f * fx / (float)Wn;
    rely = (c_y - qcy) * ((float)Hn * 0.5f);
    relx = (c_x - qcx) * ((float)Wn * 0.5f);
    rrev = ey * ((float)Hn * 0.5f);
}

// Kernel 1: compute the 4 phase-specialized pw matrices (576x3 each, incl. b2).
// grid = (7, 4): blockIdx.y = phase, blockIdx.x = output chunk of 256.
__global__ __launch_bounds__(256) void pw_kernel(
    const float* __restrict__ coord, const float* __restrict__ cell,
    const float* __restrict__ w1, const float* __restrict__ b1,
    const float* __restrict__ w2, const float* __restrict__ b2,
    float* __restrict__ pw) {
    __shared__ float hdd[HIDn];
    const int p  = blockIdx.y;          // phase 0..3 -> (py,px)
    const int py = p >> 1, px = p & 1;
    const int q  = py * QWn + px;       // representative query (Y=py, X=px), batch 0

    int iy, ix; float rely, relx, rrev;
    coord_math(coord, cell, 0, q, iy, ix, rely, relx, rrev);

    // hidden layer: thread j computes hdd[j]
    const int j = threadIdx.x;
    {
        float h = b1[j] + rely * w1[j] + relx * w1[HIDn + j] + rrev * w1[2 * HIDn + j];
        hdd[j] = fmaxf(h, 0.0f);
    }
    __syncthreads();

    const int t = blockIdx.x * 256 + threadIdx.x;
    if (t < OUTn) {
        float s = b2[t];
        #pragma unroll 8
        for (int jj = 0; jj < HIDn; ++jj)
            s = fmaf(hdd[jj], w2[(size_t)jj * OUTn + t], s);
        pw[p * OUTn + t] = s;
    }
}

// Kernel 2: per 8x8-LR tile (16x16 HR), stage full patch cube + 4 pw matrices in
// LDS, each thread produces one HR pixel's 3 outputs.
// grid = (8, 8, 4): x -> LR col tile, y -> LR row tile, z -> batch. block = 256.
__global__ __launch_bounds__(256) void metasr_main(
    const float* __restrict__ feat, const float* __restrict__ coord,
    const float* __restrict__ cell, const float* __restrict__ pw,
    float* __restrict__ out) {
    __shared__ float  patch[Cn * 100];      // [c][10][10], 25.6 KB
    __shared__ float4 pwl4[4 * 576];        // [p][k]{o0,o1,o2,pad}, 36.9 KB

    const int tid = threadIdx.x;
    const int bz  = blockIdx.z;
    const int i0  = blockIdx.y * 8;         // LR tile origin
    const int j0  = blockIdx.x * 8;

    // ---- stage patch cube (zero-padded halo) ----
    for (int e = tid; e < Cn * 100; e += 256) {
        const int c  = e / 100;
        const int r  = e - c * 100;
        const int yy = r / 10;
        const int xx = r - yy * 10;
        const int gy = i0 - 1 + yy;
        const int gx = j0 - 1 + xx;
        float v = 0.0f;
        if ((unsigned)gy < (unsigned)Hn && (unsigned)gx < (unsigned)Wn)
            v = feat[(((size_t)bz * Cn + c) * Hn + gy) * Wn + gx];
        patch[e] = v;
    }
    // ---- stage pw into padded float4 layout ----
    float* pwl = (float*)pwl4;
    for (int e = tid; e < 4 * OUTn; e += 256) {
        const int p = e / OUTn;
        const int t = e - p * OUTn;
        const int k = t / 3;
        const int o = t - k * 3;
        pwl[((p * 576) + k) * 4 + o] = pw[e];
    }
    __syncthreads();

    // ---- thread -> HR pixel mapping: wave = phase, lane = 8x8 LR pixel ----
    const int wv   = tid >> 6;
    const int lane = tid & 63;
    const int li   = lane >> 3, lj = lane & 7;
    const int Y = (i0 + li) * 2 + (wv >> 1);
    const int X = (j0 + lj) * 2 + (wv & 1);

    int iy, ix; float rely, relx, rrev;
    coord_math(coord, cell, bz, Y * QWn + X, iy, ix, rely, relx, rrev);
    (void)rrev;
    int pc = ((rely > 0.25f) ? 2 : 0) + ((relx > 0.25f) ? 1 : 0);
    pc = __builtin_amdgcn_readfirstlane(pc);   // wave-uniform by construction

    int bri = iy - i0;            // should equal li
    int bci = ix - j0;            // should equal lj
    bri = min(max(bri, 0), 7);
    bci = min(max(bci, 0), 7);

    const float4* wbase = &pwl4[pc * 576];
    const float*  pb    = &patch[bri * 10 + bci];

    float a0 = 0.0f, a1 = 0.0f, a2 = 0.0f;
    #pragma unroll 2
    for (int c = 0; c < Cn; ++c) {
        const float*  pr = pb + c * 100;
        const float4* wr = wbase + c * 9;
        #pragma unroll
        for (int ky = 0; ky < 3; ++ky) {
            #pragma unroll
            for (int kx = 0; kx < 3; ++kx) {
                const float  v = pr[ky * 10 + kx];
                const float4 w = wr[ky * 3 + kx];
                a0 = fmaf(v, w.x, a0);
                a1 = fmaf(v, w.y, a1);
                a2 = fmaf(v, w.z, a2);
            }
        }
    }

    const size_t oidx = ((size_t)bz * Qn + (size_t)Y * QWn + X) * 3;
    out[oidx + 0] = a0;
    out[oidx + 1] = a1;
    out[oidx + 2] = a2;
}

extern "C" void kernel_launch(void* const* d_in, const int* in_sizes, int n_in,
                              void* d_out, int out_size, void* d_ws, size_t ws_size,
                              hipStream_t stream) {
    const float* feat  = (const float*)d_in[0];
    const float* coord = (const float*)d_in[1];
    const float* cell  = (const float*)d_in[2];
    const float* w1    = (const float*)d_in[3];
    const float* b1    = (const float*)d_in[4];
    const float* w2    = (const float*)d_in[5];
    const float* b2    = (const float*)d_in[6];
    float* out = (float*)d_out;
    float* pw  = (float*)d_ws;   // 4*1728 floats = 27,648 B scratch

    pw_kernel<<<dim3(7, 4, 1), 256, 0, stream>>>(coord, cell, w1, b1, w2, b2, pw);
    metasr_main<<<dim3(8, 8, 4), 256, 0, stream>>>(feat, coord, cell, pw, out);
}

// Round 2
// 95.554 us; speedup vs baseline: 1.1063x; 1.1063x over previous
//
#include <hip/hip_runtime.h>
#include <math.h>

#define QHn 128
#define QWn 128
#define Qn  16384
#define Hn  64
#define Wn  64
#define Cn  64
#define Bn  4
#define HIDn 256
#define OUTn 1728   // C*9*3
#define PWPAD 28    // padded floats per channel (112 B, 16B-aligned stride)
#define PWSTRIDE (Cn * PWPAD)   // 1792 floats per phase
#define EPSf 1e-6f

// Reference-faithful coordinate math (fp32, same op order/rounding as jnp).
__device__ __forceinline__ void coord_math(const float* __restrict__ coord,
                                           const float* __restrict__ cell,
                                           int b, int q,
                                           int& iy, int& ix,
                                           float& rely, float& relx, float& rrev) {
    const size_t base = ((size_t)b * Qn + q) * 2;
    const float cy = coord[base + 0];
    const float cx = coord[base + 1];
    const float ey = cell[base + 0];
    const float ex = cell[base + 1];
    const float c_y = cy - ey * 0.5f;
    const float c_x = cx - ex * 0.5f;
    const float cqy = fminf(fmaxf(c_y + EPSf, -1.0f + EPSf), 1.0f - EPSf);
    const float cqx = fminf(fmaxf(c_x + EPSf, -1.0f + EPSf), 1.0f - EPSf);
    float fy = rintf(((cqy + 1.0f) * (float)Hn - 1.0f) * 0.5f);  // round-half-even
    float fx = rintf(((cqx + 1.0f) * (float)Wn - 1.0f) * 0.5f);
    fy = fminf(fmaxf(fy, 0.0f), (float)(Hn - 1));
    fx = fminf(fmaxf(fx, 0.0f), (float)(Wn - 1));
    iy = (int)fy;
    ix = (int)fx;
    const float qcy = -1.0f + 2.0f * fy / (float)Hn;
    const float qcx = -1.0f + 2.0f * fx / (float)Wn;
    rely = (c_y - qcy) * ((float)Hn * 0.5f);
    relx = (c_x - qcx) * ((float)Wn * 0.5f);
    rrev = ey * ((float)Hn * 0.5f);
}

// Kernel 1: the 4 phase-specialized pw matrices, written in padded layout
// pw[p*PWSTRIDE + c*PWPAD + (tap*3+o)].  grid=(27,4) block=256.
// Block computes 64 outputs (t0..t0+63); 4 wave-slices split the HID reduction.
__global__ __launch_bounds__(256) void pw_kernel(
    const float* __restrict__ coord, const float* __restrict__ cell,
    const float* __restrict__ w1, const float* __restrict__ b1,
    const float* __restrict__ w2, const float* __restrict__ b2,
    float* __restrict__ pw) {
    __shared__ float hdd[HIDn];
    __shared__ float part[4 * 64];
    const int p  = blockIdx.y;          // phase 0..3 -> (py,px)
    const int py = p >> 1, px = p & 1;
    const int q  = py * QWn + px;       // representative query, batch 0

    int iy, ix; float rely, relx, rrev;
    coord_math(coord, cell, 0, q, iy, ix, rely, relx, rrev);

    const int tid = threadIdx.x;
    {   // hidden layer: thread j computes hdd[j]
        const int j = tid;
        float h = b1[j] + rely * w1[j] + relx * w1[HIDn + j] + rrev * w1[2 * HIDn + j];
        hdd[j] = fmaxf(h, 0.0f);
    }
    __syncthreads();

    const int tloc  = tid & 63;
    const int slice = tid >> 6;
    const int t     = blockIdx.x * 64 + tloc;   // 0..1727

    float s = 0.0f;
    const int j0 = slice * 64;
    #pragma unroll 16
    for (int jj = 0; jj < 64; ++jj)
        s = fmaf(hdd[j0 + jj], w2[(size_t)(j0 + jj) * OUTn + t], s);
    part[slice * 64 + tloc] = s;
    __syncthreads();

    if (tid < 64) {
        const int tt = blockIdx.x * 64 + tid;
        float v = b2[tt] + part[tid] + part[64 + tid] + part[128 + tid] + part[192 + tid];
        const int c   = tt / 27;
        const int rem = tt - c * 27;
        pw[p * PWSTRIDE + c * PWPAD + rem] = v;
    }
}

// Kernel 2: per 8x8-LR tile (16x16 HR). Patch cube in LDS; phase weights read
// via wave-uniform (scalar-promotable) global loads. grid=(8,8,4) block=256.
__global__ __launch_bounds__(256) void metasr_main(
    const float* __restrict__ feat, const float* __restrict__ coord,
    const float* __restrict__ cell, const float* __restrict__ pw,
    float* __restrict__ out) {
    __shared__ float patch[Cn * 100];      // [c][10][10], 25.6 KB

    const int tid = threadIdx.x;
    const int bz  = blockIdx.z;
    const int i0  = blockIdx.y * 8;        // LR tile origin
    const int j0  = blockIdx.x * 8;

    // ---- stage patch cube (zero-padded halo) ----
    for (int e = tid; e < Cn * 100; e += 256) {
        const int c  = e / 100;
        const int r  = e - c * 100;
        const int yy = r / 10;
        const int xx = r - yy * 10;
        const int gy = i0 - 1 + yy;
        const int gx = j0 - 1 + xx;
        float v = 0.0f;
        if ((unsigned)gy < (unsigned)Hn && (unsigned)gx < (unsigned)Wn)
            v = feat[(((size_t)bz * Cn + c) * Hn + gy) * Wn + gx];
        patch[e] = v;
    }
    __syncthreads();

    // ---- thread -> HR pixel: wave = phase, lane = 8x8 LR pixel ----
    const int wv   = tid >> 6;
    const int lane = tid & 63;
    const int li   = lane >> 3, lj = lane & 7;
    const int Y = (i0 + li) * 2 + (wv >> 1);
    const int X = (j0 + lj) * 2 + (wv & 1);

    int iy, ix; float rely, relx, rrev;
    coord_math(coord, cell, bz, Y * QWn + X, iy, ix, rely, relx, rrev);
    (void)rrev;
    int pc = ((rely > 0.25f) ? 2 : 0) + ((relx > 0.25f) ? 1 : 0);
    pc = __builtin_amdgcn_readfirstlane(pc);   // wave-uniform phase -> scalar loads

    int bri = iy - i0;
    int bci = ix - j0;
    bri = min(max(bri, 0), 7);
    bci = min(max(bci, 0), 7);

    const float* __restrict__ wb = pw + (size_t)pc * PWSTRIDE;  // uniform base
    const float* pb = &patch[bri * 10 + bci];

    float a0 = 0.0f, a1 = 0.0f, a2 = 0.0f;
    #pragma unroll 2
    for (int c = 0; c < Cn; ++c) {
        // 27 wave-uniform weight loads (112B-aligned block) -> s_load_dwordx4/x8
        float ww[27];
        #pragma unroll
        for (int i = 0; i < 27; ++i)
            ww[i] = wb[c * PWPAD + i];
        const float* pr = pb + c * 100;
        #pragma unroll
        for (int ky = 0; ky < 3; ++ky) {
            #pragma unroll
            for (int kx = 0; kx < 3; ++kx) {
                const float v = pr[ky * 10 + kx];
                const int   w = (ky * 3 + kx) * 3;
                a0 = fmaf(v, ww[w + 0], a0);
                a1 = fmaf(v, ww[w + 1], a1);
                a2 = fmaf(v, ww[w + 2], a2);
            }
        }
    }

    const size_t oidx = ((size_t)bz * Qn + (size_t)Y * QWn + X) * 3;
    out[oidx + 0] = a0;
    out[oidx + 1] = a1;
    out[oidx + 2] = a2;
}

extern "C" void kernel_launch(void* const* d_in, const int* in_sizes, int n_in,
                              void* d_out, int out_size, void* d_ws, size_t ws_size,
                              hipStream_t stream) {
    const float* feat  = (const float*)d_in[0];
    const float* coord = (const float*)d_in[1];
    const float* cell  = (const float*)d_in[2];
    const float* w1    = (const float*)d_in[3];
    const float* b1    = (const float*)d_in[4];
    const float* w2    = (const float*)d_in[5];
    const float* b2    = (const float*)d_in[6];
    float* out = (float*)d_out;
    float* pw  = (float*)d_ws;   // 4*PWSTRIDE floats = 28,672 B scratch

    pw_kernel<<<dim3(27, 4, 1), 256, 0, stream>>>(coord, cell, w1, b1, w2, b2, pw);
    metasr_main<<<dim3(8, 8, 4), 256, 0, stream>>>(feat, coord, cell, pw, out);
}